// Round 1
// baseline (1158.779 us; speedup 1.0000x reference)
//
#include <hip/hip_runtime.h>
#include <cstdint>
#include <cstddef>

#define MN 100000      // n_nodes
#define NE 2000000     // n_edges
// IN_C=512, HID=64, OUT_C=32

// ---------------- degree via atomics ----------------
__global__ __launch_bounds__(256) void deg_kernel(const int* __restrict__ dst,
                                                  float* __restrict__ degbuf, int nE) {
    int idx = blockIdx.x * 256 + threadIdx.x;
    int stride = gridDim.x * 256;
    for (int e = idx; e < nE; e += stride)
        atomicAdd(&degbuf[dst[e]], 1.0f);
}

__global__ __launch_bounds__(256) void dinv_kernel(float* __restrict__ d, int n) {
    int i = blockIdx.x * 256 + threadIdx.x;
    if (i < n) d[i] = rsqrtf(d[i] + 1.0f);
}

// ---------------- GEMM1: hpre = x @ W1   (M x 512) @ (512 x 64) ----------------
__global__ __launch_bounds__(256) void gemm_x_w1(const float* __restrict__ x,
                                                 const float* __restrict__ W,
                                                 float* __restrict__ out, int M) {
    __shared__ float xs[16][68];   // [k][m], BM=64 (+4 pad)
    __shared__ float ws[16][68];   // [k][n], N=64 (+4 pad)
    const int tid = threadIdx.x;
    const int bm  = blockIdx.x * 64;
    const int tx  = tid & 15, ty = tid >> 4;
    const int lrow = tid >> 2;            // 0..63 node row (x load)
    const int lkq  = (tid & 3) * 4;       // k quad (x load)
    const int wr   = tid >> 4;            // 0..15 k row (W load)
    const int wcq  = (tid & 15) * 4;      // col quad (W load)
    float acc[4][4] = {{0.f}};

    for (int k0 = 0; k0 < 512; k0 += 16) {
        float4 xv = make_float4(0.f, 0.f, 0.f, 0.f);
        if (bm + lrow < M)
            xv = *reinterpret_cast<const float4*>(x + (size_t)(bm + lrow) * 512 + k0 + lkq);
        xs[lkq + 0][lrow] = xv.x;
        xs[lkq + 1][lrow] = xv.y;
        xs[lkq + 2][lrow] = xv.z;
        xs[lkq + 3][lrow] = xv.w;
        *reinterpret_cast<float4*>(&ws[wr][wcq]) =
            *reinterpret_cast<const float4*>(W + (size_t)(k0 + wr) * 64 + wcq);
        __syncthreads();
#pragma unroll
        for (int kk = 0; kk < 16; ++kk) {
            float4 a = *reinterpret_cast<const float4*>(&xs[kk][ty * 4]);
            float4 b = *reinterpret_cast<const float4*>(&ws[kk][tx * 4]);
            acc[0][0] += a.x * b.x; acc[0][1] += a.x * b.y; acc[0][2] += a.x * b.z; acc[0][3] += a.x * b.w;
            acc[1][0] += a.y * b.x; acc[1][1] += a.y * b.y; acc[1][2] += a.y * b.z; acc[1][3] += a.y * b.w;
            acc[2][0] += a.z * b.x; acc[2][1] += a.z * b.y; acc[2][2] += a.z * b.z; acc[2][3] += a.z * b.w;
            acc[3][0] += a.w * b.x; acc[3][1] += a.w * b.y; acc[3][2] += a.w * b.z; acc[3][3] += a.w * b.w;
        }
        __syncthreads();
    }
#pragma unroll
    for (int i = 0; i < 4; ++i) {
        int node = bm + ty * 4 + i;
        if (node < M) {
            float4 v = make_float4(acc[i][0], acc[i][1], acc[i][2], acc[i][3]);
            *reinterpret_cast<float4*>(out + (size_t)node * 64 + tx * 4) = v;
        }
    }
}

// ---------------- edge aggregation: agg[dst] += h[src] * dinv[src]*dinv[dst] ----------------
// one wave per edge, lane = channel (64 channels)
__global__ __launch_bounds__(256) void edge_agg64(const float* __restrict__ h,
                                                  const int* __restrict__ src,
                                                  const int* __restrict__ dst,
                                                  const float* __restrict__ dinv,
                                                  float* __restrict__ agg, int nE) {
    const int lane = threadIdx.x & 63;
    int wave = (blockIdx.x * 256 + threadIdx.x) >> 6;
    const int nw = (gridDim.x * 256) >> 6;
    for (int e = wave; e < nE; e += nw) {
        int s = src[e];
        int d = dst[e];
        float norm = dinv[s] * dinv[d];
        float v = h[(size_t)s * 64 + lane] * norm;
        atomicAdd(&agg[(size_t)d * 64 + lane], v);
    }
}

// ---------------- finalize layer1: h = relu(agg + dinv^2*hpre + b1) ----------------
__global__ __launch_bounds__(256) void finalize_relu(const float* __restrict__ agg,
                                                     const float* __restrict__ hpre,
                                                     const float* __restrict__ dinv,
                                                     const float* __restrict__ bias,
                                                     float* __restrict__ out, int M) {
    int idx = blockIdx.x * 256 + threadIdx.x;
    int stride = gridDim.x * 256;
    int total = M * 64;
    for (int i = idx; i < total; i += stride) {
        int node = i >> 6, c = i & 63;
        float di = dinv[node];
        float v = agg[i] + di * di * hpre[i] + bias[c];
        out[i] = v > 0.f ? v : 0.f;
    }
}

// ---------------- finalize layer2 + dual GEMM + bias -> out ----------------
// Af = A + dinv^2*h ; mu = Af@Wmu + bmu ; ls = Af@Wls + bls
__global__ __launch_bounds__(256) void gemm2_out(const float* __restrict__ A,
                                                 const float* __restrict__ h,
                                                 const float* __restrict__ dinv,
                                                 const float* __restrict__ Wmu,
                                                 const float* __restrict__ bmu,
                                                 const float* __restrict__ Wls,
                                                 const float* __restrict__ bls,
                                                 float* __restrict__ out, int M) {
    __shared__ float Wc[64][68];   // k x (mu cols | ls cols)
    __shared__ float Af[64][68];   // 64 nodes x 64
    const int tid = threadIdx.x;
    const int node0 = blockIdx.x * 64;

    for (int t = tid; t < 4096; t += 256) {
        int k = t >> 6, c = t & 63;
        Wc[k][c] = (c < 32) ? Wmu[k * 32 + c] : Wls[k * 32 + (c - 32)];
    }
    for (int t = tid; t < 4096; t += 256) {
        int r = t >> 6, c = t & 63;
        int node = node0 + r;
        float v = 0.f;
        if (node < M) {
            float di = dinv[node];
            size_t off = (size_t)node * 64 + c;
            v = A[off] + di * di * h[off];
        }
        Af[r][c] = v;
    }
    __syncthreads();

    const int r = tid >> 2;   // local node row 0..63
    const int g = tid & 3;    // col group: 0,1 -> mu ; 2,3 -> logstd
    float accv[16];
#pragma unroll
    for (int j = 0; j < 16; ++j) accv[j] = 0.f;
    for (int k = 0; k < 64; ++k) {
        float a = Af[r][k];
#pragma unroll
        for (int j = 0; j < 16; ++j) accv[j] += a * Wc[k][g * 16 + j];
    }
    int node = node0 + r;
    if (node < M) {
        if (g < 2) {
            int c0 = g * 16;
#pragma unroll
            for (int j = 0; j < 16; ++j)
                out[(size_t)node * 32 + c0 + j] = accv[j] + bmu[c0 + j];
        } else {
            int c0 = (g - 2) * 16;
#pragma unroll
            for (int j = 0; j < 16; ++j)
                out[(size_t)M * 32 + (size_t)node * 32 + c0 + j] = accv[j] + bls[c0 + j];
        }
    }
}

extern "C" void kernel_launch(void* const* d_in, const int* in_sizes, int n_in,
                              void* d_out, int out_size, void* d_ws, size_t ws_size,
                              hipStream_t stream) {
    const float* x   = (const float*)d_in[0];
    const int*   ei  = (const int*)d_in[1];
    const float* W1  = (const float*)d_in[2];
    const float* b1  = (const float*)d_in[3];
    const float* Wmu = (const float*)d_in[4];
    const float* bmu = (const float*)d_in[5];
    const float* Wls = (const float*)d_in[6];
    const float* bls = (const float*)d_in[7];
    float* out = (float*)d_out;

    const int M = MN, E = NE;
    const int* src = ei;
    const int* dst = ei + E;

    const size_t feat_bytes = (size_t)M * 64 * sizeof(float);
    char* w = (char*)d_ws;
    float* hpre = (float*)(w);                      // reused as A after layer 1
    float* agg1 = (float*)(w + feat_bytes);
    float* h    = (float*)(w + 2 * feat_bytes);
    float* dinv = (float*)(w + 3 * feat_bytes);
    float* A    = hpre;

    hipMemsetAsync(dinv, 0, M * sizeof(float), stream);
    hipMemsetAsync(agg1, 0, feat_bytes, stream);

    deg_kernel<<<2048, 256, 0, stream>>>(dst, dinv, E);
    dinv_kernel<<<(M + 255) / 256, 256, 0, stream>>>(dinv, M);

    gemm_x_w1<<<(M + 63) / 64, 256, 0, stream>>>(x, W1, hpre, M);
    edge_agg64<<<2048, 256, 0, stream>>>(hpre, src, dst, dinv, agg1, E);
    finalize_relu<<<2048, 256, 0, stream>>>(agg1, hpre, dinv, b1, h, M);

    hipMemsetAsync(A, 0, feat_bytes, stream);       // hpre dead now; reuse as A
    edge_agg64<<<2048, 256, 0, stream>>>(h, src, dst, dinv, A, E);
    gemm2_out<<<(M + 63) / 64, 256, 0, stream>>>(A, h, dinv, Wmu, bmu, Wls, bls, out, M);
}

// Round 2
// 707.293 us; speedup vs baseline: 1.6383x; 1.6383x over previous
//
#include <hip/hip_runtime.h>
#include <cstdint>
#include <cstddef>

#define MN 100000      // n_nodes
#define NE 2000000     // n_edges
// IN_C=512, HID=64, OUT_C=32

// ---------------- in-degree histogram (int atomics, L2-resident, cheap) ----------------
__global__ __launch_bounds__(256) void hist_kernel(const int* __restrict__ dst,
                                                   int* __restrict__ cnt, int nE) {
    int idx = blockIdx.x * 256 + threadIdx.x;
    int stride = gridDim.x * 256;
    for (int e = idx; e < nE; e += stride)
        atomicAdd(&cnt[dst[e]], 1);
}

__global__ __launch_bounds__(256) void dinv_kernel(const int* __restrict__ cnt,
                                                   float* __restrict__ dinv, int n) {
    int i = blockIdx.x * 256 + threadIdx.x;
    if (i < n) dinv[i] = rsqrtf((float)cnt[i] + 1.0f);
}

// ---------------- exclusive scan of cnt -> rowptr (+cursor copy), single block ----------------
__global__ __launch_bounds__(1024) void scan_kernel(const int* __restrict__ cnt,
                                                    int* __restrict__ rowptr,
                                                    int* __restrict__ cursor, int n) {
    __shared__ int wsum[16];
    const int lane = threadIdx.x & 63, wid = threadIdx.x >> 6;
    int carry = 0;
    for (int base = 0; base < n; base += 1024) {
        int i = base + threadIdx.x;
        int v = (i < n) ? cnt[i] : 0;
        int x = v;
#pragma unroll
        for (int off = 1; off < 64; off <<= 1) {
            int t = __shfl_up(x, off);
            if (lane >= off) x += t;
        }
        if (lane == 63) wsum[wid] = x;
        __syncthreads();
        if (wid == 0) {
            int w = (lane < 16) ? wsum[lane] : 0;
#pragma unroll
            for (int off = 1; off < 16; off <<= 1) {
                int t = __shfl_up(w, off);
                if (lane >= off) w += t;
            }
            if (lane < 16) wsum[lane] = w;
        }
        __syncthreads();
        int waveoff = (wid > 0) ? wsum[wid - 1] : 0;
        int excl = carry + waveoff + x - v;
        if (i < n) { rowptr[i] = excl; cursor[i] = excl; }
        carry += wsum[15];
        __syncthreads();
    }
    if (threadIdx.x == 0) rowptr[n] = carry;
}

// ---------------- scatter edges into CSR slots ----------------
__global__ __launch_bounds__(256) void scatter_kernel(const int* __restrict__ src,
                                                      const int* __restrict__ dst,
                                                      int* __restrict__ cursor,
                                                      int* __restrict__ csr, int nE) {
    int idx = blockIdx.x * 256 + threadIdx.x;
    int stride = gridDim.x * 256;
    for (int e = idx; e < nE; e += stride) {
        int p = atomicAdd(&cursor[dst[e]], 1);
        csr[p] = src[e];
    }
}

// ---------------- GEMM1: hs1 = (x @ W1) * dinv[node]   (M x 512) @ (512 x 64) ----------------
__global__ __launch_bounds__(256) void gemm_x_w1(const float* __restrict__ x,
                                                 const float* __restrict__ W,
                                                 const float* __restrict__ dinv,
                                                 float* __restrict__ out, int M) {
    __shared__ float xs[16][68];   // [k][m]
    __shared__ float ws[16][68];   // [k][n]
    const int tid = threadIdx.x;
    const int bm  = blockIdx.x * 64;
    const int tx  = tid & 15, ty = tid >> 4;
    const int lrow = tid >> 2;
    const int lkq  = (tid & 3) * 4;
    const int wr   = tid >> 4;
    const int wcq  = (tid & 15) * 4;
    float acc[4][4] = {{0.f}};

    for (int k0 = 0; k0 < 512; k0 += 16) {
        float4 xv = make_float4(0.f, 0.f, 0.f, 0.f);
        if (bm + lrow < M)
            xv = *reinterpret_cast<const float4*>(x + (size_t)(bm + lrow) * 512 + k0 + lkq);
        xs[lkq + 0][lrow] = xv.x;
        xs[lkq + 1][lrow] = xv.y;
        xs[lkq + 2][lrow] = xv.z;
        xs[lkq + 3][lrow] = xv.w;
        *reinterpret_cast<float4*>(&ws[wr][wcq]) =
            *reinterpret_cast<const float4*>(W + (size_t)(k0 + wr) * 64 + wcq);
        __syncthreads();
#pragma unroll
        for (int kk = 0; kk < 16; ++kk) {
            float4 a = *reinterpret_cast<const float4*>(&xs[kk][ty * 4]);
            float4 b = *reinterpret_cast<const float4*>(&ws[kk][tx * 4]);
            acc[0][0] += a.x * b.x; acc[0][1] += a.x * b.y; acc[0][2] += a.x * b.z; acc[0][3] += a.x * b.w;
            acc[1][0] += a.y * b.x; acc[1][1] += a.y * b.y; acc[1][2] += a.y * b.z; acc[1][3] += a.y * b.w;
            acc[2][0] += a.z * b.x; acc[2][1] += a.z * b.y; acc[2][2] += a.z * b.z; acc[2][3] += a.z * b.w;
            acc[3][0] += a.w * b.x; acc[3][1] += a.w * b.y; acc[3][2] += a.w * b.z; acc[3][3] += a.w * b.w;
        }
        __syncthreads();
    }
#pragma unroll
    for (int i = 0; i < 4; ++i) {
        int node = bm + ty * 4 + i;
        if (node < M) {
            float di = dinv[node];
            float4 v = make_float4(acc[i][0] * di, acc[i][1] * di, acc[i][2] * di, acc[i][3] * di);
            *reinterpret_cast<float4*>(out + (size_t)node * 64 + tx * 4) = v;
        }
    }
}

// ---------------- layer1 aggregate (gather CSR) + ReLU + prescale for layer2 ----------------
// hs2[d] = relu(dinv[d]*(sum_{in(d)} hs1[src] + hs1[d]) + b1) * dinv[d]
__global__ __launch_bounds__(256) void agg1_kernel(const float* __restrict__ hs1,
                                                   const int* __restrict__ rowptr,
                                                   const int* __restrict__ csr,
                                                   const float* __restrict__ dinv,
                                                   const float* __restrict__ b1,
                                                   float* __restrict__ hs2, int M) {
    const int lane = threadIdx.x & 63;
    const int node = blockIdx.x * 4 + (threadIdx.x >> 6);
    if (node >= M) return;
    const int st = rowptr[node], en = rowptr[node + 1];
    float acc = hs1[(size_t)node * 64 + lane];   // self-loop
    int i = st;
    for (; i + 1 < en; i += 2) {
        int s0 = csr[i], s1 = csr[i + 1];
        float v0 = hs1[(size_t)s0 * 64 + lane];
        float v1 = hs1[(size_t)s1 * 64 + lane];
        acc += v0;
        acc += v1;
    }
    if (i < en) acc += hs1[(size_t)csr[i] * 64 + lane];
    float di = dinv[node];
    float hv = di * acc + b1[lane];
    hv = hv > 0.f ? hv : 0.f;
    hs2[(size_t)node * 64 + lane] = hv * di;
}

// ---------------- layer2 aggregate: A[d] = dinv[d]*(sum hs2[src] + hs2[d]) ----------------
__global__ __launch_bounds__(256) void agg2_kernel(const float* __restrict__ hs2,
                                                   const int* __restrict__ rowptr,
                                                   const int* __restrict__ csr,
                                                   const float* __restrict__ dinv,
                                                   float* __restrict__ A, int M) {
    const int lane = threadIdx.x & 63;
    const int node = blockIdx.x * 4 + (threadIdx.x >> 6);
    if (node >= M) return;
    const int st = rowptr[node], en = rowptr[node + 1];
    float acc = hs2[(size_t)node * 64 + lane];   // self-loop
    int i = st;
    for (; i + 1 < en; i += 2) {
        int s0 = csr[i], s1 = csr[i + 1];
        float v0 = hs2[(size_t)s0 * 64 + lane];
        float v1 = hs2[(size_t)s1 * 64 + lane];
        acc += v0;
        acc += v1;
    }
    if (i < en) acc += hs2[(size_t)csr[i] * 64 + lane];
    A[(size_t)node * 64 + lane] = dinv[node] * acc;
}

// ---------------- dual GEMM2 + bias -> out ----------------
__global__ __launch_bounds__(256) void gemm2_out(const float* __restrict__ A,
                                                 const float* __restrict__ Wmu,
                                                 const float* __restrict__ bmu,
                                                 const float* __restrict__ Wls,
                                                 const float* __restrict__ bls,
                                                 float* __restrict__ out, int M) {
    __shared__ float Wc[64][68];   // k x (mu cols | ls cols)
    __shared__ float Af[64][68];   // 64 nodes x 64
    const int tid = threadIdx.x;
    const int node0 = blockIdx.x * 64;

    for (int t = tid; t < 4096; t += 256) {
        int k = t >> 6, c = t & 63;
        Wc[k][c] = (c < 32) ? Wmu[k * 32 + c] : Wls[k * 32 + (c - 32)];
    }
    for (int t = tid; t < 4096; t += 256) {
        int r = t >> 6, c = t & 63;
        int node = node0 + r;
        Af[r][c] = (node < M) ? A[(size_t)node * 64 + c] : 0.f;
    }
    __syncthreads();

    const int r = tid >> 2;
    const int g = tid & 3;
    float accv[16];
#pragma unroll
    for (int j = 0; j < 16; ++j) accv[j] = 0.f;
    for (int k = 0; k < 64; ++k) {
        float a = Af[r][k];
#pragma unroll
        for (int j = 0; j < 16; ++j) accv[j] += a * Wc[k][g * 16 + j];
    }
    int node = node0 + r;
    if (node < M) {
        if (g < 2) {
            int c0 = g * 16;
#pragma unroll
            for (int j = 0; j < 16; ++j)
                out[(size_t)node * 32 + c0 + j] = accv[j] + bmu[c0 + j];
        } else {
            int c0 = (g - 2) * 16;
#pragma unroll
            for (int j = 0; j < 16; ++j)
                out[(size_t)M * 32 + (size_t)node * 32 + c0 + j] = accv[j] + bls[c0 + j];
        }
    }
}

extern "C" void kernel_launch(void* const* d_in, const int* in_sizes, int n_in,
                              void* d_out, int out_size, void* d_ws, size_t ws_size,
                              hipStream_t stream) {
    const float* x   = (const float*)d_in[0];
    const int*   ei  = (const int*)d_in[1];
    const float* W1  = (const float*)d_in[2];
    const float* b1  = (const float*)d_in[3];
    const float* Wmu = (const float*)d_in[4];
    const float* bmu = (const float*)d_in[5];
    const float* Wls = (const float*)d_in[6];
    const float* bls = (const float*)d_in[7];
    float* out = (float*)d_out;

    const int M = MN, E = NE;
    const int* src = ei;
    const int* dst = ei + E;

    const size_t feat_bytes = (size_t)M * 64 * sizeof(float);
    char* w = (char*)d_ws;
    size_t off = 0;
    auto alloc = [&](size_t bytes) {
        char* p = w + off;
        off = (off + bytes + 255) & ~(size_t)255;
        return p;
    };
    int*   cnt    = (int*)  alloc((size_t)M * 4);
    int*   rowptr = (int*)  alloc((size_t)(M + 1) * 4);
    int*   cursor = (int*)  alloc((size_t)M * 4);
    int*   csr    = (int*)  alloc((size_t)E * 4);
    float* dinv   = (float*)alloc((size_t)M * 4);
    float* hs1    = (float*)alloc(feat_bytes);   // reused as A after agg1
    float* hs2    = (float*)alloc(feat_bytes);
    float* A      = hs1;

    hipMemsetAsync(cnt, 0, (size_t)M * 4, stream);

    hist_kernel<<<2048, 256, 0, stream>>>(dst, cnt, E);
    dinv_kernel<<<(M + 255) / 256, 256, 0, stream>>>(cnt, dinv, M);
    scan_kernel<<<1, 1024, 0, stream>>>(cnt, rowptr, cursor, M);
    scatter_kernel<<<2048, 256, 0, stream>>>(src, dst, cursor, csr, E);

    gemm_x_w1<<<(M + 63) / 64, 256, 0, stream>>>(x, W1, dinv, hs1, M);
    agg1_kernel<<<(M + 3) / 4, 256, 0, stream>>>(hs1, rowptr, csr, dinv, b1, hs2, M);
    agg2_kernel<<<(M + 3) / 4, 256, 0, stream>>>(hs2, rowptr, csr, dinv, A, M);
    gemm2_out<<<(M + 63) / 64, 256, 0, stream>>>(A, Wmu, bmu, Wls, bls, out, M);
}